// Round 1
// 69.895 us; speedup vs baseline: 1.0340x; 1.0340x over previous
//
#include <hip/hip_runtime.h>

// SoftToHardEncoder: B=16, L=16, H=64, W=64, NUM_CODES=64
// Outputs (concat, fp32): soft_symbols[B,H,W,L], hard_symbols[B,H,W,L], idxes[B,H,W,L]
//
// O(1)-per-element algorithm (replaces the 64-code inner loop):
//   Sort codes per row l. For query z with k = #{w <= z}:
//     sum  = e^{-z} * P[k]  + e^{z} * Q[k]     (P = prefix of e^{w},  Q = suffix of e^{-w})
//     wsum = e^{-z} * PW[k] + e^{z} * QW[k]    (PW/QW with w * e^{+-w})
//   argmin(|z-w|) is one of the two sorted neighbors; compared on exact fp32
//   distances with first-original-index tie-break (matches jnp.argmin).
// A tiny prep kernel builds tables in d_ws (stable rank-sort + wave scans;
// suffix sums via DIRECT reverse scan to avoid total-minus-prefix cancellation).

namespace {
constexpr int kL = 16;
constexpr int kC = 64;
constexpr int kHW = 64 * 64;            // 4096
constexpr int kN = 16 * kHW * kL;       // 1,048,576 per output
constexpr float kLog2e = 1.44269504088896340736f;
constexpr float kBig = 3.0e38f;

// Workspace layout (float4 units):
//   cand[16][65] : (w_left, w_right, oidx_left, oidx_right) indexed by k
//   pqt [16][65] : (P, Qsuf, PW, QWsuf) indexed by k
//   wsrt packed  : sorted w, 16 rows, row stride 67 floats (odd -> bank spread)
constexpr int kRowEnt = 65;
constexpr int kCandF4 = kL * kRowEnt;            // 1040
constexpr int kTblF4 = 2 * kCandF4;              // 2080 (cand | pqt)
constexpr int kWsStride = 67;
constexpr int kWsF4 = (kL * kWsStride + 3) / 4;  // 268
}

__global__ __launch_bounds__(64) void prep_kernel(
    const float* __restrict__ codes, float4* __restrict__ wsout)
{
    const int l = blockIdx.x;        // 16 blocks, one row per wave
    const int lane = threadIdx.x;    // 64
    const float w = codes[l * kC + lane];

    // Stable rank (ties broken by original index) == stable ascending sort.
    int rank = 0;
#pragma unroll
    for (int j = 0; j < kC; ++j) {
        const float wj = __shfl(w, j);
        rank += (wj < w || (wj == w && j < lane)) ? 1 : 0;
    }

    __shared__ float sw[kC];
    __shared__ int so[kC];
    sw[rank] = w;
    so[rank] = lane;
    __syncthreads();
    const float wsrt = sw[lane];
    const int osrt = so[lane];

    const float p = exp2f(wsrt * kLog2e);    // e^{+w}
    const float q = exp2f(-wsrt * kLog2e);   // e^{-w}
    const float pw = p * wsrt;
    const float qw = q * wsrt;

    // Inclusive prefix scans (ascending) for p, pw; inclusive suffix scans
    // (descending, direct — no cancellation) for q, qw.
    float ip = p, ipw = pw, sq = q, sqw = qw;
#pragma unroll
    for (int d = 1; d < 64; d <<= 1) {
        float t;
        t = __shfl_up(ip, d);    if (lane >= d) ip += t;
        t = __shfl_up(ipw, d);   if (lane >= d) ipw += t;
        t = __shfl_down(sq, d);  if (lane < 64 - d) sq += t;
        t = __shfl_down(sqw, d); if (lane < 64 - d) sqw += t;
    }
    // Exclusive prefixes at this lane (sum over sorted positions < lane).
    float Pexc = __shfl_up(ip, 1);
    float PWexc = __shfl_up(ipw, 1);
    if (lane == 0) { Pexc = 0.0f; PWexc = 0.0f; }

    float4* cand = wsout;
    float4* pqt = wsout + kCandF4;
    float* wpk = reinterpret_cast<float*>(wsout + kTblF4);

    pqt[l * kRowEnt + lane] = make_float4(Pexc, sq, PWexc, sqw);
    float wprev = __shfl_up(wsrt, 1);
    int oprev = __shfl_up(osrt, 1);
    if (lane == 0) { wprev = -kBig; oprev = 0; }
    cand[l * kRowEnt + lane] =
        make_float4(wprev, wsrt, (float)oprev, (float)osrt);
    if (lane == 63) {
        // k = 64: every code <= z.  ip/ipw at lane 63 are full totals.
        pqt[l * kRowEnt + 64] = make_float4(ip, 0.0f, ipw, 0.0f);
        cand[l * kRowEnt + 64] = make_float4(wsrt, kBig, (float)osrt, 0.0f);
    }
    wpk[l * kWsStride + lane] = wsrt;
}

__global__ __launch_bounds__(256, 4) void soft_to_hard_kernel(
    const float* __restrict__ z,
    const float4* __restrict__ tbl_g,
    float* __restrict__ out)
{
    __shared__ float4 tbl[kTblF4];    // cand[16][65] | pqt[16][65]
    __shared__ float4 swr4[kWsF4];    // packed sorted w, stride 67 floats/row

    const int tid = threadIdx.x;
    const int l = tid & (kL - 1);
    const int base = blockIdx.x * 1024 + tid;   // this thread's 4 gids: +256*i

    // Issue z loads first so they fly under the table staging.
    float zv[4];
#pragma unroll
    for (int i = 0; i < 4; ++i) {
        const int gid = base + 256 * i;
        const int b = gid >> 16;
        const int hw = (gid >> 4) & (kHW - 1);
        zv[i] = z[(b << 16) + (l << 12) + hw];
    }

    // Stage tables: 2348 float4 = 37.5 KB, coalesced 16B loads.
    for (int t = tid; t < kTblF4; t += 256) tbl[t] = tbl_g[t];
    for (int t = tid; t < kWsF4; t += 256) swr4[t] = tbl_g[kTblF4 + t];
    __syncthreads();

    const float* wrow = reinterpret_cast<const float*>(swr4) + l * kWsStride;
    const float4* crow = tbl + l * kRowEnt;
    const float4* prow = tbl + kCandF4 + l * kRowEnt;

    // Branchless binary search, 4 independent chains interleaved for ILP:
    // k[i] = #{sorted w <= z}.  7 dependent ds_read_b32 per element.
    int k[4] = {0, 0, 0, 0};
#pragma unroll
    for (int s = 32; s >= 1; s >>= 1) {
#pragma unroll
        for (int i = 0; i < 4; ++i)
            if (wrow[k[i] + s - 1] <= zv[i]) k[i] += s;
    }
#pragma unroll
    for (int i = 0; i < 4; ++i)
        if (wrow[k[i]] <= zv[i]) k[i] += 1;

#pragma unroll
    for (int i = 0; i < 4; ++i) {
        const int gid = base + 256 * i;
        const float zi = zv[i];
        const float t = zi * kLog2e;
        const float E = exp2f(t);     // e^{+z}
        const float Ei = exp2f(-t);   // e^{-z}

        const float4 pq = prow[k[i]];
        const float sum = Ei * pq.x + E * pq.y;
        const float wsum = Ei * pq.z + E * pq.w;
        const float soft = wsum / sum;

        const float4 cd = crow[k[i]];
        const float dl = zi - cd.x;   // exact fp32 |z - w_left|  (w_left <= z)
        const float dr = cd.y - zi;   // exact fp32 |z - w_right| (w_right > z)
        const bool left = (dl < dr) || ((dl == dr) && (cd.z < cd.w));
        const float hard = left ? cd.x : cd.y;
        const float idxf = left ? cd.z : cd.w;

        out[gid] = soft;
        out[kN + gid] = hard;
        out[2 * kN + gid] = idxf;
    }
}

extern "C" void kernel_launch(void* const* d_in, const int* in_sizes, int n_in,
                              void* d_out, int out_size, void* d_ws, size_t ws_size,
                              hipStream_t stream) {
    const float* z = (const float*)d_in[0];      // [16,16,64,64] fp32
    const float* codes = (const float*)d_in[1];  // [16,64] fp32
    float* out = (float*)d_out;                  // 3 * 1,048,576 fp32
    float4* tbl = (float4*)d_ws;                 // ~37.6 KB of workspace

    prep_kernel<<<16, 64, 0, stream>>>(codes, tbl);
    soft_to_hard_kernel<<<1024, 256, 0, stream>>>(z, tbl, out);
}

// Round 2
// 69.137 us; speedup vs baseline: 1.0454x; 1.0110x over previous
//
#include <hip/hip_runtime.h>

// SoftToHardEncoder: B=16, L=16, H=64, W=64, NUM_CODES=64
// Outputs (concat, fp32): soft_symbols[B,H,W,L], hard_symbols[B,H,W,L], idxes[B,H,W,L]
//
// O(1)-per-element algorithm (replaces the 64-code inner loop):
//   Sort codes per row l. For query z with k = #{w <= z}:
//     sum  = e^{-z} * P[k]  + e^{z} * Q[k]     (P = prefix of e^{w},  Q = suffix of e^{-w})
//     wsum = e^{-z} * PW[k] + e^{z} * QW[k]    (PW/QW with w * e^{+-w})
//   argmin(|z-w|) is one of the two sorted neighbors; compared on exact fp32
//   distances with first-original-index tie-break (matches jnp.argmin).
// A tiny prep kernel builds tables in d_ws (stable rank-sort + wave scans;
// suffix sums via DIRECT reverse scan to avoid total-minus-prefix cancellation).
//
// R1 change: thread = 4 CONSECUTIVE gids (base = blk*1024 + tid*4) ->
//   - stores become 3x global_store_dwordx4 (was 12 scalar stores)
//   - z wave footprint = fully-consumed 64B lines (was 16B-of-64B, 4x overfetch)

namespace {
constexpr int kL = 16;
constexpr int kC = 64;
constexpr int kHW = 64 * 64;            // 4096
constexpr int kN = 16 * kHW * kL;       // 1,048,576 per output
constexpr float kLog2e = 1.44269504088896340736f;
constexpr float kBig = 3.0e38f;

// Workspace layout (float4 units):
//   cand[16][65] : (w_left, w_right, oidx_left, oidx_right) indexed by k
//   pqt [16][65] : (P, Qsuf, PW, QWsuf) indexed by k
//   wsrt packed  : sorted w, 16 rows, row stride 67 floats (odd -> bank spread)
constexpr int kRowEnt = 65;
constexpr int kCandF4 = kL * kRowEnt;            // 1040
constexpr int kTblF4 = 2 * kCandF4;              // 2080 (cand | pqt)
constexpr int kWsStride = 67;
constexpr int kWsF4 = (kL * kWsStride + 3) / 4;  // 268
}

__global__ __launch_bounds__(64) void prep_kernel(
    const float* __restrict__ codes, float4* __restrict__ wsout)
{
    const int l = blockIdx.x;        // 16 blocks, one row per wave
    const int lane = threadIdx.x;    // 64
    const float w = codes[l * kC + lane];

    // Stable rank (ties broken by original index) == stable ascending sort.
    int rank = 0;
#pragma unroll
    for (int j = 0; j < kC; ++j) {
        const float wj = __shfl(w, j);
        rank += (wj < w || (wj == w && j < lane)) ? 1 : 0;
    }

    __shared__ float sw[kC];
    __shared__ int so[kC];
    sw[rank] = w;
    so[rank] = lane;
    __syncthreads();
    const float wsrt = sw[lane];
    const int osrt = so[lane];

    const float p = exp2f(wsrt * kLog2e);    // e^{+w}
    const float q = exp2f(-wsrt * kLog2e);   // e^{-w}
    const float pw = p * wsrt;
    const float qw = q * wsrt;

    // Inclusive prefix scans (ascending) for p, pw; inclusive suffix scans
    // (descending, direct — no cancellation) for q, qw.
    float ip = p, ipw = pw, sq = q, sqw = qw;
#pragma unroll
    for (int d = 1; d < 64; d <<= 1) {
        float t;
        t = __shfl_up(ip, d);    if (lane >= d) ip += t;
        t = __shfl_up(ipw, d);   if (lane >= d) ipw += t;
        t = __shfl_down(sq, d);  if (lane < 64 - d) sq += t;
        t = __shfl_down(sqw, d); if (lane < 64 - d) sqw += t;
    }
    // Exclusive prefixes at this lane (sum over sorted positions < lane).
    float Pexc = __shfl_up(ip, 1);
    float PWexc = __shfl_up(ipw, 1);
    if (lane == 0) { Pexc = 0.0f; PWexc = 0.0f; }

    float4* cand = wsout;
    float4* pqt = wsout + kCandF4;
    float* wpk = reinterpret_cast<float*>(wsout + kTblF4);

    pqt[l * kRowEnt + lane] = make_float4(Pexc, sq, PWexc, sqw);
    float wprev = __shfl_up(wsrt, 1);
    int oprev = __shfl_up(osrt, 1);
    if (lane == 0) { wprev = -kBig; oprev = 0; }
    cand[l * kRowEnt + lane] =
        make_float4(wprev, wsrt, (float)oprev, (float)osrt);
    if (lane == 63) {
        // k = 64: every code <= z.  ip/ipw at lane 63 are full totals.
        pqt[l * kRowEnt + 64] = make_float4(ip, 0.0f, ipw, 0.0f);
        cand[l * kRowEnt + 64] = make_float4(wsrt, kBig, (float)osrt, 0.0f);
    }
    wpk[l * kWsStride + lane] = wsrt;
}

__global__ __launch_bounds__(256, 4) void soft_to_hard_kernel(
    const float* __restrict__ z,
    const float4* __restrict__ tbl_g,
    float* __restrict__ out)
{
    __shared__ float4 tbl[kTblF4];    // cand[16][65] | pqt[16][65]
    __shared__ float4 swr4[kWsF4];    // packed sorted w, stride 67 floats/row

    const int tid = threadIdx.x;
    const int base = blockIdx.x * 1024 + (tid << 2);  // 4 consecutive gids
    const int l0 = base & (kL - 1);                   // 4*(tid&3)
    const int hw = (base >> 4) & (kHW - 1);           // same for all 4 gids
    const int b  = base >> 16;

    // z is [B, L, H, W]; issue loads first so they fly under table staging.
    // Wave footprint: per l-plane, 16 consecutive floats = full 64B lines.
    const float* zp = z + (b << 16) + hw;
    float zv[4];
#pragma unroll
    for (int j = 0; j < 4; ++j) zv[j] = zp[(l0 + j) << 12];

    // Stage tables: 2348 float4 = 37.5 KB, coalesced 16B loads.
    for (int t = tid; t < kTblF4; t += 256) tbl[t] = tbl_g[t];
    for (int t = tid; t < kWsF4; t += 256) swr4[t] = tbl_g[kTblF4 + t];
    __syncthreads();

    const float* swr = reinterpret_cast<const float*>(swr4);
    const float* wrow[4];
#pragma unroll
    for (int j = 0; j < 4; ++j) wrow[j] = swr + (l0 + j) * kWsStride;

    // Branchless binary search, 4 independent chains interleaved for ILP:
    // k[j] = #{sorted w <= z}.  7 dependent ds_read_b32 per element.
    int k[4] = {0, 0, 0, 0};
#pragma unroll
    for (int s = 32; s >= 1; s >>= 1) {
#pragma unroll
        for (int j = 0; j < 4; ++j)
            if (wrow[j][k[j] + s - 1] <= zv[j]) k[j] += s;
    }
#pragma unroll
    for (int j = 0; j < 4; ++j)
        if (wrow[j][k[j]] <= zv[j]) k[j] += 1;

    float sres[4], hres[4], xres[4];
#pragma unroll
    for (int j = 0; j < 4; ++j) {
        const float zi = zv[j];
        const float t = zi * kLog2e;
        const float E = exp2f(t);     // e^{+z}
        const float Ei = exp2f(-t);   // e^{-z}

        const int row = (l0 + j) * kRowEnt + k[j];
        const float4 pq = tbl[kCandF4 + row];
        const float sum = Ei * pq.x + E * pq.y;
        const float wsum = Ei * pq.z + E * pq.w;
        sres[j] = wsum / sum;

        const float4 cd = tbl[row];
        const float dl = zi - cd.x;   // exact fp32 |z - w_left|  (w_left <= z)
        const float dr = cd.y - zi;   // exact fp32 |z - w_right| (w_right > z)
        const bool left = (dl < dr) || ((dl == dr) && (cd.z < cd.w));
        hres[j] = left ? cd.x : cd.y;
        xres[j] = left ? cd.z : cd.w;
    }

    // 3x coalesced dwordx4 stores (base is 16B-aligned).
    *reinterpret_cast<float4*>(out + base) =
        make_float4(sres[0], sres[1], sres[2], sres[3]);
    *reinterpret_cast<float4*>(out + kN + base) =
        make_float4(hres[0], hres[1], hres[2], hres[3]);
    *reinterpret_cast<float4*>(out + 2 * kN + base) =
        make_float4(xres[0], xres[1], xres[2], xres[3]);
}

extern "C" void kernel_launch(void* const* d_in, const int* in_sizes, int n_in,
                              void* d_out, int out_size, void* d_ws, size_t ws_size,
                              hipStream_t stream) {
    const float* z = (const float*)d_in[0];      // [16,16,64,64] fp32
    const float* codes = (const float*)d_in[1];  // [16,64] fp32
    float* out = (float*)d_out;                  // 3 * 1,048,576 fp32
    float4* tbl = (float4*)d_ws;                 // ~37.6 KB of workspace

    prep_kernel<<<16, 64, 0, stream>>>(codes, tbl);
    soft_to_hard_kernel<<<1024, 256, 0, stream>>>(z, tbl, out);
}